// Round 7
// baseline (252.797 us; speedup 1.0000x reference)
//
#include <hip/hip_runtime.h>
#include <hip/hip_bf16.h>

#define D_DIM 256
#define K_CODES 1024
#define HW 1024
#define N_VEC 32768
#define N_ELEM 8388608ull

typedef __attribute__((ext_vector_type(8))) short bf16x8;
typedef __attribute__((ext_vector_type(4))) float f32x4;
typedef __attribute__((ext_vector_type(2))) float f32x2;

static __device__ __forceinline__ unsigned short f2bf(float x) {
    union { __hip_bfloat16 h; unsigned short u; } cvt;
    cvt.h = __float2bfloat16(x);
    return cvt.u;
}

// ---------------------------------------------------------------------------
// Kernel A (fused prep): codebook -> bf16 B-fragment order + codebook norms
// + zero counts/lossacc. 128 blocks x 256.
// ---------------------------------------------------------------------------
__global__ __launch_bounds__(256) void prep_kernel(const float* __restrict__ cb,
                                                   unsigned short* __restrict__ cbb,
                                                   float* __restrict__ cnorm,
                                                   int* __restrict__ counts,
                                                   float* __restrict__ lossacc) {
    int slot = blockIdx.x * 256 + threadIdx.x;  // 0 .. 32767
    // --- cbprep: fragment-order bf16 codebook ---
    {
        int lane = slot & 63;
        int dchunk = (slot >> 6) & 7;
        int ktile = slot >> 9;
        int code = ktile * 16 + (lane & 15);
        int d0 = dchunk * 32 + (lane >> 4) * 8;
        const float4* src = (const float4*)(cb + (size_t)code * D_DIM + d0);
        float4 v0 = src[0], v1 = src[1];
        int4 o;
        o.x = f2bf(v0.x) | ((unsigned)f2bf(v0.y) << 16);
        o.y = f2bf(v0.z) | ((unsigned)f2bf(v0.w) << 16);
        o.z = f2bf(v1.x) | ((unsigned)f2bf(v1.y) << 16);
        o.w = f2bf(v1.z) | ((unsigned)f2bf(v1.w) << 16);
        *(int4*)(cbb + (size_t)slot * 8) = o;
    }
    // --- cnorm (8 lanes per code) + zero counts/lossacc ---
    if (slot < 8192) {
        if (slot < K_CODES) counts[slot] = 0;
        if (slot == K_CODES) lossacc[0] = 0.f;
        int k = slot >> 3;
        int part = slot & 7;
        const float4* row = (const float4*)(cb + (size_t)k * D_DIM + part * 32);
        float s = 0.f;
#pragma unroll
        for (int i = 0; i < 8; i++) {
            float4 v = row[i];
            s = fmaf(v.x, v.x, s);
            s = fmaf(v.y, v.y, s);
            s = fmaf(v.z, v.z, s);
            s = fmaf(v.w, v.w, s);
        }
        s += __shfl_xor(s, 1);
        s += __shfl_xor(s, 2);
        s += __shfl_xor(s, 4);
        if (part == 0) cnorm[k] = s;
    }
}

// ---------------------------------------------------------------------------
// Kernel B (FUSED, PIPELINED): argmin MFMA + quantize/STE + loss + one-hot.
// R5 instrument: T(fused) ~= 80us ~= the ZERO-OVERLAP sum of its pipe budgets
// (z 5.5 + LDS 20 + MFMA 8 + DMA 7.5 + out 5.5 + enc 21 + misc). The two
// lockstep co-resident blocks per CU gave no phase diversity. Fix: grid 256
// (1 block/CU); each block runs TWO 64-row groups in an outer loop. Group 0's
// ~11us enc-store drain overlaps group 1's prologue + LDS main loop (store
// queue is fire-and-forget), staging DMA overlaps compute. Cross-group LDS
// hazards: next group's chunk-0 stage writes Bbuf[0] while stragglers read
// only Bbuf[1] (chunk15, after the c=15 barrier); bk is rewritten only after
// group g+1's 16 chunk barriers, long past group g's epilogue reads. Loss
// accumulates across groups, one atomic at the end.
// cbb aliases enc rows 0..128: group-0 blocks 0..2 (rows <192) skip enc;
// finalize writes those rows after stream-order completion.
// ---------------------------------------------------------------------------
__global__ __launch_bounds__(256, 2) void fused_vq(const float* __restrict__ z,
                                                   const unsigned short* __restrict__ cbb,
                                                   const float* __restrict__ cnorm,
                                                   const float* __restrict__ cb,
                                                   int* __restrict__ indices,
                                                   int* __restrict__ counts,
                                                   float* __restrict__ out,
                                                   float* __restrict__ enc,
                                                   float* __restrict__ lossacc) {
    __shared__ unsigned short Bbuf[2][4 * 8 * 64 * 8];  // 2 x 32 KB
    __shared__ int bk[64];
    __shared__ float wsum[4];
    const int t = threadIdx.x;
    const int lane = t & 63;
    const int w = t >> 6;        // wave 0..3
    const int row = lane & 15;
    const int dq = (lane >> 4) * 8;
    const int col = lane & 15;
    float ls = 0.f;  // loss partial, accumulated across both groups

    for (int g = 0; g < 2; ++g) {
        const int gb = g * 256 + blockIdx.x;  // virtual block 0..511
        const int nt0 = gb * 4 + w;           // wave owns ONE ntile
        const int n = nt0 * 16 + row;         // this lane's z row
        const int b = n >> 10;
        const int hw = n & (HW - 1);

        // ---- prologue: load z f32 (kept in regs) + pack bf16 A fragments ----
        float zf[8][8];
        bf16x8 Ar[8];
#pragma unroll
        for (int dc = 0; dc < 8; dc++) {
            const float* src = z + (((size_t)(b * D_DIM + dc * 32 + dq)) << 10) + hw;
            union { bf16x8 v; unsigned short u[8]; } pk;
#pragma unroll
            for (int j = 0; j < 8; j++) {
                zf[dc][j] = src[(size_t)j << 10];
                pk.u[j] = f2bf(zf[dc][j]);
            }
            Ar[dc] = pk.v;
        }

        // ---- async stage of chunk 0 (Bbuf[0] free: prior group ended on [1]) ----
        {
            const unsigned int* gsrc = (const unsigned int*)cbb;
            unsigned int* l = (unsigned int*)Bbuf[0];
#pragma unroll
            for (int p = 0; p < 8; p++) {
                int off = (p * 256 + t) * 4;
                __builtin_amdgcn_global_load_lds(
                    (const __attribute__((address_space(1))) unsigned int*)(gsrc + off),
                    (__attribute__((address_space(3))) unsigned int*)(l + off), 16, 0, 0);
            }
        }

        float bestd[4];
        int bestk[4];
#pragma unroll
        for (int r = 0; r < 4; r++) { bestd[r] = 3.4e38f; bestk[r] = 0; }

        for (int c = 0; c < 16; c++) {
            const int cur = c & 1;
            __syncthreads();  // drains vmcnt -> Bbuf[cur] ready; all waves off other buf
            if (c < 15) {
                const unsigned int* gsrc = (const unsigned int*)(cbb + (size_t)(c + 1) * 16384);
                unsigned int* l = (unsigned int*)Bbuf[cur ^ 1];
#pragma unroll
                for (int p = 0; p < 8; p++) {
                    int off = (p * 256 + t) * 4;
                    __builtin_amdgcn_global_load_lds(
                        (const __attribute__((address_space(1))) unsigned int*)(gsrc + off),
                        (__attribute__((address_space(3))) unsigned int*)(l + off), 16, 0, 0);
                }
            }
            const unsigned short* Bb = Bbuf[cur];
#pragma unroll
            for (int half = 0; half < 2; half++) {  // 2 ktiles at a time
                bf16x8 bb[2][8];
#pragma unroll
                for (int kt2 = 0; kt2 < 2; kt2++)
#pragma unroll
                    for (int dc = 0; dc < 8; dc++)
                        bb[kt2][dc] = *(const bf16x8*)
                            &Bb[(((half * 2 + kt2) * 8 + dc) * 64 + lane) * 8];
                f32x4 acc[2];
#pragma unroll
                for (int kt2 = 0; kt2 < 2; kt2++) acc[kt2] = (f32x4){0.f, 0.f, 0.f, 0.f};
#pragma unroll
                for (int dc = 0; dc < 8; dc++)
#pragma unroll
                    for (int kt2 = 0; kt2 < 2; kt2++)
                        acc[kt2] = __builtin_amdgcn_mfma_f32_16x16x32_bf16(
                            Ar[dc], bb[kt2][dc], acc[kt2], 0, 0, 0);
                // running best (k ascending => first-min tiebreak)
#pragma unroll
                for (int kt2 = 0; kt2 < 2; kt2++) {
                    int k = (c * 4 + half * 2 + kt2) * 16 + col;
                    float cn = cnorm[k];
#pragma unroll
                    for (int r = 0; r < 4; r++) {
                        float sc = fmaf(-2.0f, acc[kt2][r], cn);
                        if (sc < bestd[r]) { bestd[r] = sc; bestk[r] = k; }
                    }
                }
            }
        }

        // ---- reduce across the 16 columns; stash winning codes in LDS ----
#pragma unroll
        for (int r = 0; r < 4; r++) {
            float dd = bestd[r];
            int kk = bestk[r];
#pragma unroll
            for (int off = 8; off >= 1; off >>= 1) {
                float d2 = __shfl_xor(dd, off);
                int k2 = __shfl_xor(kk, off);
                if (d2 < dd || (d2 == dd && k2 < kk)) { dd = d2; kk = k2; }
            }
            if ((lane & 15) == 0) {
                int nloc = w * 16 + (lane >> 4) * 4 + r;  // block-local n
                bk[nloc] = kk;
                indices[gb * 64 + nloc] = kk;
                atomicAdd(&counts[kk], 1);
            }
        }
        __syncthreads();  // bk visible to all waves

        // ---- epilogue 1: quantize + STE output + loss (z still in VGPRs) ----
        const int mycode = bk[w * 16 + row];
        const float4* crow4 = (const float4*)(cb + (size_t)mycode * D_DIM);
        float* obase = out + (((size_t)b * D_DIM) << 10) + hw;
#pragma unroll
        for (int dc = 0; dc < 8; dc++) {
            const int dbase = dc * 32 + dq;
            float4 qa = crow4[(dbase >> 2) + 0];
            float4 qb = crow4[(dbase >> 2) + 1];
            float qv[8] = {qa.x, qa.y, qa.z, qa.w, qb.x, qb.y, qb.z, qb.w};
#pragma unroll
            for (int j = 0; j < 8; j++) {
                float zv = zf[dc][j];
                float e = qv[j] - zv;
                obase[(size_t)(dbase + j) << 10] = zv + e;
                ls = fmaf(e, e, ls);
            }
        }

        // ---- epilogue 2: one-hot enc rows (rows <192 alias cbb: deferred) ----
        const int n0 = gb * 64;
        if (n0 >= 192) {
#pragma unroll 4
            for (int j = 0; j < 64; j++) {
                int idx = bk[j];
                float* rowp = enc + (size_t)(n0 + j) * 1024;
                if (t < 255) {
                    int k0 = 2 + t * 4;
                    f32x4 v;
                    v.x = (k0 == idx) ? 1.f : 0.f;
                    v.y = (k0 + 1 == idx) ? 1.f : 0.f;
                    v.z = (k0 + 2 == idx) ? 1.f : 0.f;
                    v.w = (k0 + 3 == idx) ? 1.f : 0.f;
                    __builtin_nontemporal_store(v, (f32x4*)(rowp + k0));
                } else {
                    f32x2 hd, tl;
                    hd.x = (0 == idx) ? 1.f : 0.f;
                    hd.y = (1 == idx) ? 1.f : 0.f;
                    tl.x = (1022 == idx) ? 1.f : 0.f;
                    tl.y = (1023 == idx) ? 1.f : 0.f;
                    __builtin_nontemporal_store(hd, (f32x2*)rowp);
                    __builtin_nontemporal_store(tl, (f32x2*)(rowp + 1022));
                }
            }
        }
    }  // group loop

    // ---- loss reduction (both groups) ----
#pragma unroll
    for (int off = 32; off >= 1; off >>= 1) ls += __shfl_down(ls, off);
    if (lane == 0) wsum[w] = ls;
    __syncthreads();
    if (t == 0) atomicAdd(lossacc, wsum[0] + wsum[1] + wsum[2] + wsum[3]);
}

// ---------------------------------------------------------------------------
// Kernel E: finalize loss + perplexity; also writes the 192 deferred enc rows
// (they alias cbb during fused_vq; safe now by stream ordering). 192 blocks.
// ---------------------------------------------------------------------------
__global__ __launch_bounds__(256) void finalize_kernel(const int* __restrict__ counts,
                                                       const float* __restrict__ lossacc,
                                                       const int* __restrict__ indices,
                                                       float* __restrict__ enc,
                                                       float* __restrict__ out_scalars) {
    const int t = threadIdx.x;
    // deferred one-hot row
    {
        int nrow = blockIdx.x;  // 0..191
        int idx = indices[nrow];
        float* rowp = enc + (size_t)nrow * 1024;
        if (t < 255) {
            int k0 = 2 + t * 4;
            f32x4 v;
            v.x = (k0 == idx) ? 1.f : 0.f;
            v.y = (k0 + 1 == idx) ? 1.f : 0.f;
            v.z = (k0 + 2 == idx) ? 1.f : 0.f;
            v.w = (k0 + 3 == idx) ? 1.f : 0.f;
            __builtin_nontemporal_store(v, (f32x4*)(rowp + k0));
        } else {
            f32x2 hd, tl;
            hd.x = (0 == idx) ? 1.f : 0.f;
            hd.y = (1 == idx) ? 1.f : 0.f;
            tl.x = (1022 == idx) ? 1.f : 0.f;
            tl.y = (1023 == idx) ? 1.f : 0.f;
            __builtin_nontemporal_store(hd, (f32x2*)rowp);
            __builtin_nontemporal_store(tl, (f32x2*)(rowp + 1022));
        }
    }
    if (blockIdx.x != 0) return;
    float s = 0.f;
#pragma unroll
    for (int i = 0; i < 4; i++) {
        int k = t + i * 256;
        float p = (float)counts[k] * (1.0f / 32768.0f);
        s += p * logf(p + 1e-10f);
    }
#pragma unroll
    for (int off = 32; off >= 1; off >>= 1) s += __shfl_down(s, off);
    __shared__ float red[4];
    if ((t & 63) == 0) red[t >> 6] = s;
    __syncthreads();
    if (t == 0) {
        float tot = red[0] + red[1] + red[2] + red[3];
        out_scalars[0] = 1.25f * (lossacc[0] * (1.0f / 8388608.0f));  // q + beta*e
        out_scalars[1] = expf(-tot);                                  // perplexity
    }
}

// ---------------------------------------------------------------------------
extern "C" void kernel_launch(void* const* d_in, const int* in_sizes, int n_in,
                              void* d_out, int out_size, void* d_ws, size_t ws_size,
                              hipStream_t stream) {
    const float* z = (const float*)d_in[0];   // [32,256,32,32]
    const float* cb = (const float*)d_in[1];  // [1024,256]
    float* out = (float*)d_out;
    char* wsb = (char*)d_ws;

    float* cnorm = (float*)wsb;             // 1024 f32
    int* counts = (int*)(wsb + 4096);       // 1024 i32
    float* lossacc = (float*)(wsb + 8192);  // 1 f32
    int* indices = (int*)(wsb + 16384);     // 32768 i32

    float* quant = out;             // [0, 8388608)
    float* scal = out + N_ELEM;     // loss @ +0, perplexity @ +1
    float* enc = out + N_ELEM + 2;  // [8388610, +33554432)

    // cbb (512KB, bf16 fragment order) aliases enc rows 0..128; those rows
    // are deferred to finalize_kernel (see fused_vq comment).
    unsigned short* cbb = (unsigned short*)(out + 8388612);  // 16B-aligned

    hipLaunchKernelGGL(prep_kernel, dim3(128), dim3(256), 0, stream, cb, cbb,
                       cnorm, counts, lossacc);
    hipLaunchKernelGGL(fused_vq, dim3(256), dim3(256), 0, stream, z, cbb,
                       cnorm, cb, indices, counts, quant, enc, lossacc);
    hipLaunchKernelGGL(finalize_kernel, dim3(192), dim3(256), 0, stream, counts,
                       lossacc, indices, enc, scal);
}

// Round 8
// 248.065 us; speedup vs baseline: 1.0191x; 1.0191x over previous
//
#include <hip/hip_runtime.h>
#include <hip/hip_bf16.h>

#define D_DIM 256
#define K_CODES 1024
#define HW 1024
#define N_VEC 32768
#define N_ELEM 8388608ull

typedef __attribute__((ext_vector_type(8))) short bf16x8;
typedef __attribute__((ext_vector_type(4))) float f32x4;
typedef __attribute__((ext_vector_type(2))) float f32x2;

static __device__ __forceinline__ unsigned short f2bf(float x) {
    union { __hip_bfloat16 h; unsigned short u; } cvt;
    cvt.h = __float2bfloat16(x);
    return cvt.u;
}

// ---------------------------------------------------------------------------
// Kernel A (fused prep): codebook -> bf16 B-fragment order + codebook norms
// + zero counts/lossacc. 128 blocks x 256.
// ---------------------------------------------------------------------------
__global__ __launch_bounds__(256) void prep_kernel(const float* __restrict__ cb,
                                                   unsigned short* __restrict__ cbb,
                                                   float* __restrict__ cnorm,
                                                   int* __restrict__ counts,
                                                   float* __restrict__ lossacc) {
    int slot = blockIdx.x * 256 + threadIdx.x;  // 0 .. 32767
    // --- cbprep: fragment-order bf16 codebook ---
    {
        int lane = slot & 63;
        int dchunk = (slot >> 6) & 7;
        int ktile = slot >> 9;
        int code = ktile * 16 + (lane & 15);
        int d0 = dchunk * 32 + (lane >> 4) * 8;
        const float4* src = (const float4*)(cb + (size_t)code * D_DIM + d0);
        float4 v0 = src[0], v1 = src[1];
        int4 o;
        o.x = f2bf(v0.x) | ((unsigned)f2bf(v0.y) << 16);
        o.y = f2bf(v0.z) | ((unsigned)f2bf(v0.w) << 16);
        o.z = f2bf(v1.x) | ((unsigned)f2bf(v1.y) << 16);
        o.w = f2bf(v1.z) | ((unsigned)f2bf(v1.w) << 16);
        *(int4*)(cbb + (size_t)slot * 8) = o;
    }
    // --- cnorm (8 lanes per code) + zero counts/lossacc ---
    if (slot < 8192) {
        if (slot < K_CODES) counts[slot] = 0;
        if (slot == K_CODES) lossacc[0] = 0.f;
        int k = slot >> 3;
        int part = slot & 7;
        const float4* row = (const float4*)(cb + (size_t)k * D_DIM + part * 32);
        float s = 0.f;
#pragma unroll
        for (int i = 0; i < 8; i++) {
            float4 v = row[i];
            s = fmaf(v.x, v.x, s);
            s = fmaf(v.y, v.y, s);
            s = fmaf(v.z, v.z, s);
            s = fmaf(v.w, v.w, s);
        }
        s += __shfl_xor(s, 1);
        s += __shfl_xor(s, 2);
        s += __shfl_xor(s, 4);
        if (part == 0) cnorm[k] = s;
    }
}

// ---------------------------------------------------------------------------
// Kernel B (FUSED, DEEP-PIPELINED): argmin MFMA + quantize/STE + loss + enc.
// R7 counters: dur 102us, ALL pipes <25% (hbm 25%, mfma 6.5%, valu 11%),
// occupancy 10%, bytes minimal => LATENCY-BOUND on the per-chunk barrier
// chain (__syncthreads drains vmcnt(0) -> just-issued stage gets <1 compute
// phase to land). Fix = guide T3+T4: counted vmcnt, loads span barriers.
//   - 512 blocks (2 blocks/CU, best measured), wave owns ONE ntile (16 n).
//   - 32 chunks of 16KB (2 ktiles), FOUR LDS buffers, prefetch depth 3:
//     raw s_barrier + s_waitcnt vmcnt(8) in main loop (never 0); tail peels
//     with vmcnt(8/4/0). Stage for chunk c now has ~3 compute phases to land.
//   - cnorm staged to LDS in prologue: the in-loop score read is ds_read
//     (lgkmcnt), NOT a VMEM load -- a VMEM consumer inside the loop would
//     force the compiler to emit vmcnt(0) (FIFO) and kill the pipeline.
//   - sched_barrier(0) after each barrier: stop hipcc hoisting LDS reads /
//     MFMA above the inline-asm waits (guide rule #18).
// Per-wave vmcnt counts the wave's OWN 4 DMA quarters per chunk; the barrier
// upgrades "my quarter landed" to "whole chunk landed".
// Buffer safety: stage(c+3) (post-barrier-c) writes buf[(c+3)&3], last read
// at chunk c-1; barrier c happens-after all waves' c-1 reads. cbb aliases
// enc rows 0..128: blocks 0..2 skip enc; finalize writes rows 0..191.
// ---------------------------------------------------------------------------
__global__ __launch_bounds__(256, 2) void fused_vq(const float* __restrict__ z,
                                                   const unsigned short* __restrict__ cbb,
                                                   const float* __restrict__ cnorm,
                                                   const float* __restrict__ cb,
                                                   int* __restrict__ indices,
                                                   int* __restrict__ counts,
                                                   float* __restrict__ out,
                                                   float* __restrict__ enc,
                                                   float* __restrict__ lossacc) {
    __shared__ unsigned short Bbuf[4][8192];  // 4 x 16 KB
    __shared__ float cnl[1024];
    __shared__ int bk[64];
    __shared__ float wsum[4];
    const int t = threadIdx.x;
    const int lane = t & 63;
    const int w = t >> 6;                // wave 0..3
    const int nt0 = blockIdx.x * 4 + w;  // wave owns ONE ntile
    const int row = lane & 15;
    const int dq = (lane >> 4) * 8;
    const int col = lane & 15;
    const int n = nt0 * 16 + row;  // this lane's z row
    const int b = n >> 10;
    const int hw = n & (HW - 1);

    // ---- cnorm -> LDS first (its vmcnt drain sees only 1 outstanding load) ----
    {
        float4 cv = ((const float4*)cnorm)[t];  // 256 x 16B = 4KB
        ((float4*)cnl)[t] = cv;
    }
    asm volatile("s_waitcnt lgkmcnt(0)" ::: "memory");  // cnl visible pre-barrier

    // ---- prologue: load z f32 (kept in regs) + pack bf16 A fragments ----
    float zf[8][8];
    bf16x8 Ar[8];
#pragma unroll
    for (int dc = 0; dc < 8; dc++) {
        const float* src = z + (((size_t)(b * D_DIM + dc * 32 + dq)) << 10) + hw;
        union { bf16x8 v; unsigned short u[8]; } pk;
#pragma unroll
        for (int j = 0; j < 8; j++) {
            zf[dc][j] = src[(size_t)j << 10];
            pk.u[j] = f2bf(zf[dc][j]);
        }
        Ar[dc] = pk.v;
    }

    // ---- staging helper: chunk c = global ktiles 2c,2c+1 = 16KB ----
    auto stage = [&](int c) {
        const unsigned int* gsrc = (const unsigned int*)cbb + (size_t)c * 4096;
        unsigned int* l = (unsigned int*)Bbuf[c & 3];
#pragma unroll
        for (int p = 0; p < 4; p++) {
            int off = p * 1024 + t * 4;
            __builtin_amdgcn_global_load_lds(
                (const __attribute__((address_space(1))) unsigned int*)(gsrc + off),
                (__attribute__((address_space(3))) unsigned int*)(l + off), 16, 0, 0);
        }
    };

    float bestd[4];
    int bestk[4];
#pragma unroll
    for (int r = 0; r < 4; r++) { bestd[r] = 3.4e38f; bestk[r] = 0; }

    // ---- chunk compute body ----
    auto chunk_body = [&](int c) {
        const unsigned short* Bb = Bbuf[c & 3];
        bf16x8 bb[2][8];
#pragma unroll
        for (int kt = 0; kt < 2; kt++)
#pragma unroll
            for (int dc = 0; dc < 8; dc++)
                bb[kt][dc] = *(const bf16x8*)&Bb[((kt * 8 + dc) * 64 + lane) * 8];
        f32x4 acc[2];
#pragma unroll
        for (int kt = 0; kt < 2; kt++) acc[kt] = (f32x4){0.f, 0.f, 0.f, 0.f};
#pragma unroll
        for (int dc = 0; dc < 8; dc++)
#pragma unroll
            for (int kt = 0; kt < 2; kt++)
                acc[kt] = __builtin_amdgcn_mfma_f32_16x16x32_bf16(
                    Ar[dc], bb[kt][dc], acc[kt], 0, 0, 0);
        // running best (k ascending => first-min tiebreak); cn from LDS
#pragma unroll
        for (int kt = 0; kt < 2; kt++) {
            int k = (c * 2 + kt) * 16 + col;
            float cn = cnl[k];
#pragma unroll
            for (int r = 0; r < 4; r++) {
                float sc = fmaf(-2.0f, acc[kt][r], cn);
                if (sc < bestd[r]) { bestd[r] = sc; bestk[r] = k; }
            }
        }
    };

    // ---- prologue stages: depth 3 ----
    stage(0);
    stage(1);
    stage(2);

    // ---- main loop: 29 iterations with uniform vmcnt(8) + stage(c+3) ----
    for (int c = 0; c < 29; ++c) {
        asm volatile("s_waitcnt vmcnt(8)" ::: "memory");  // stage(c) landed (mine)
        __builtin_amdgcn_s_barrier();                     // ...and everyone's
        __builtin_amdgcn_sched_barrier(0);
        stage(c + 3);
        chunk_body(c);
    }
    // ---- tail peel: 29 (8 in flight), 30 (4), 31 (0) ----
    asm volatile("s_waitcnt vmcnt(8)" ::: "memory");
    __builtin_amdgcn_s_barrier();
    __builtin_amdgcn_sched_barrier(0);
    chunk_body(29);
    asm volatile("s_waitcnt vmcnt(4)" ::: "memory");
    __builtin_amdgcn_s_barrier();
    __builtin_amdgcn_sched_barrier(0);
    chunk_body(30);
    asm volatile("s_waitcnt vmcnt(0)" ::: "memory");
    __builtin_amdgcn_s_barrier();
    __builtin_amdgcn_sched_barrier(0);
    chunk_body(31);

    // ---- reduce across the 16 columns; stash winning codes in LDS ----
#pragma unroll
    for (int r = 0; r < 4; r++) {
        float dd = bestd[r];
        int kk = bestk[r];
#pragma unroll
        for (int off = 8; off >= 1; off >>= 1) {
            float d2 = __shfl_xor(dd, off);
            int k2 = __shfl_xor(kk, off);
            if (d2 < dd || (d2 == dd && k2 < kk)) { dd = d2; kk = k2; }
        }
        if ((lane & 15) == 0) {
            int nloc = w * 16 + (lane >> 4) * 4 + r;  // block-local n
            bk[nloc] = kk;
            indices[blockIdx.x * 64 + nloc] = kk;
            atomicAdd(&counts[kk], 1);
        }
    }
    __syncthreads();  // bk visible to all waves

    // ---- epilogue 1: quantize + STE output + loss (z still in VGPRs) ----
    const int mycode = bk[w * 16 + row];
    const float4* crow4 = (const float4*)(cb + (size_t)mycode * D_DIM);
    float* obase = out + (((size_t)b * D_DIM) << 10) + hw;
    float ls = 0.f;
#pragma unroll
    for (int dc = 0; dc < 8; dc++) {
        const int dbase = dc * 32 + dq;
        float4 qa = crow4[(dbase >> 2) + 0];
        float4 qb = crow4[(dbase >> 2) + 1];
        float qv[8] = {qa.x, qa.y, qa.z, qa.w, qb.x, qb.y, qb.z, qb.w};
#pragma unroll
        for (int j = 0; j < 8; j++) {
            float zv = zf[dc][j];
            float e = qv[j] - zv;
            obase[(size_t)(dbase + j) << 10] = zv + e;
            ls = fmaf(e, e, ls);
        }
    }

    // ---- epilogue 2: one-hot enc rows (rows <192 alias cbb: deferred) ----
    const int n0 = blockIdx.x * 64;
    if (n0 >= 192) {
#pragma unroll 4
        for (int j = 0; j < 64; j++) {
            int idx = bk[j];
            float* rowp = enc + (size_t)(n0 + j) * 1024;
            if (t < 255) {
                int k0 = 2 + t * 4;
                f32x4 v;
                v.x = (k0 == idx) ? 1.f : 0.f;
                v.y = (k0 + 1 == idx) ? 1.f : 0.f;
                v.z = (k0 + 2 == idx) ? 1.f : 0.f;
                v.w = (k0 + 3 == idx) ? 1.f : 0.f;
                __builtin_nontemporal_store(v, (f32x4*)(rowp + k0));
            } else {
                f32x2 hd, tl;
                hd.x = (0 == idx) ? 1.f : 0.f;
                hd.y = (1 == idx) ? 1.f : 0.f;
                tl.x = (1022 == idx) ? 1.f : 0.f;
                tl.y = (1023 == idx) ? 1.f : 0.f;
                __builtin_nontemporal_store(hd, (f32x2*)rowp);
                __builtin_nontemporal_store(tl, (f32x2*)(rowp + 1022));
            }
        }
    }

    // ---- loss reduction ----
#pragma unroll
    for (int off = 32; off >= 1; off >>= 1) ls += __shfl_down(ls, off);
    if (lane == 0) wsum[w] = ls;
    __syncthreads();
    if (t == 0) atomicAdd(lossacc, wsum[0] + wsum[1] + wsum[2] + wsum[3]);
}

// ---------------------------------------------------------------------------
// Kernel E: finalize loss + perplexity; also writes the 192 deferred enc rows
// (they alias cbb during fused_vq; safe now by stream ordering). 192 blocks.
// ---------------------------------------------------------------------------
__global__ __launch_bounds__(256) void finalize_kernel(const int* __restrict__ counts,
                                                       const float* __restrict__ lossacc,
                                                       const int* __restrict__ indices,
                                                       float* __restrict__ enc,
                                                       float* __restrict__ out_scalars) {
    const int t = threadIdx.x;
    // deferred one-hot row
    {
        int nrow = blockIdx.x;  // 0..191
        int idx = indices[nrow];
        float* rowp = enc + (size_t)nrow * 1024;
        if (t < 255) {
            int k0 = 2 + t * 4;
            f32x4 v;
            v.x = (k0 == idx) ? 1.f : 0.f;
            v.y = (k0 + 1 == idx) ? 1.f : 0.f;
            v.z = (k0 + 2 == idx) ? 1.f : 0.f;
            v.w = (k0 + 3 == idx) ? 1.f : 0.f;
            __builtin_nontemporal_store(v, (f32x4*)(rowp + k0));
        } else {
            f32x2 hd, tl;
            hd.x = (0 == idx) ? 1.f : 0.f;
            hd.y = (1 == idx) ? 1.f : 0.f;
            tl.x = (1022 == idx) ? 1.f : 0.f;
            tl.y = (1023 == idx) ? 1.f : 0.f;
            __builtin_nontemporal_store(hd, (f32x2*)rowp);
            __builtin_nontemporal_store(tl, (f32x2*)(rowp + 1022));
        }
    }
    if (blockIdx.x != 0) return;
    float s = 0.f;
#pragma unroll
    for (int i = 0; i < 4; i++) {
        int k = t + i * 256;
        float p = (float)counts[k] * (1.0f / 32768.0f);
        s += p * logf(p + 1e-10f);
    }
#pragma unroll
    for (int off = 32; off >= 1; off >>= 1) s += __shfl_down(s, off);
    __shared__ float red[4];
    if ((t & 63) == 0) red[t >> 6] = s;
    __syncthreads();
    if (t == 0) {
        float tot = red[0] + red[1] + red[2] + red[3];
        out_scalars[0] = 1.25f * (lossacc[0] * (1.0f / 8388608.0f));  // q + beta*e
        out_scalars[1] = expf(-tot);                                  // perplexity
    }
}

// ---------------------------------------------------------------------------
extern "C" void kernel_launch(void* const* d_in, const int* in_sizes, int n_in,
                              void* d_out, int out_size, void* d_ws, size_t ws_size,
                              hipStream_t stream) {
    const float* z = (const float*)d_in[0];   // [32,256,32,32]
    const float* cb = (const float*)d_in[1];  // [1024,256]
    float* out = (float*)d_out;
    char* wsb = (char*)d_ws;

    float* cnorm = (float*)wsb;             // 1024 f32
    int* counts = (int*)(wsb + 4096);       // 1024 i32
    float* lossacc = (float*)(wsb + 8192);  // 1 f32
    int* indices = (int*)(wsb + 16384);     // 32768 i32

    float* quant = out;             // [0, 8388608)
    float* scal = out + N_ELEM;     // loss @ +0, perplexity @ +1
    float* enc = out + N_ELEM + 2;  // [8388610, +33554432)

    // cbb (512KB, bf16 fragment order) aliases enc rows 0..128; those rows
    // are deferred to finalize_kernel (see fused_vq comment).
    unsigned short* cbb = (unsigned short*)(out + 8388612);  // 16B-aligned

    hipLaunchKernelGGL(prep_kernel, dim3(128), dim3(256), 0, stream, cb, cbb,
                       cnorm, counts, lossacc);
    hipLaunchKernelGGL(fused_vq, dim3(512), dim3(256), 0, stream, z, cbb,
                       cnorm, cb, indices, counts, quant, enc, lossacc);
    hipLaunchKernelGGL(finalize_kernel, dim3(192), dim3(256), 0, stream, counts,
                       lossacc, indices, enc, scal);
}